// Round 10
// baseline (808.127 us; speedup 1.0000x reference)
//
#include <hip/hip_runtime.h>

#define N_USERS  200000
#define N_ITEMS  100000
#define N_TOTAL  300000
#define EMB_DIM  64
#define N_EDGES  4000000
#define N_LAYERS 3

// fixed-capacity row layout: 64 col slots per row (Poisson(13.3): P(deg>48)~1e-20)
#define CAP_BITS 6
#define CAP (1 << CAP_BITS)          // 64
#define SENT N_TOTAL                 // zero-row sentinel index

// gather: rows per wave
#define GR 4

typedef float f32x2 __attribute__((ext_vector_type(2)));

// ---- bf16 helpers ----
__device__ __forceinline__ unsigned bfpack(float a, float b) {
    unsigned ua = __float_as_uint(a); ua = (ua + 0x7fffu + ((ua >> 16) & 1u)) >> 16;
    unsigned ub = __float_as_uint(b); ub = (ub + 0x7fffu + ((ub >> 16) & 1u)) >> 16;
    return ua | (ub << 16);
}
__device__ __forceinline__ float bflo(unsigned u) { return __uint_as_float(u << 16); }
__device__ __forceinline__ float bfhi(unsigned u) { return __uint_as_float(u & 0xffff0000u); }
__device__ __forceinline__ f32x2 bf2(unsigned u) {
    f32x2 t; t.x = bflo(u); t.y = bfhi(u); return t;
}

// ---- scatter: deg count + direct write into fixed-capacity row slots ----
// No partition, no scan, no LDS: pos = atomicAdd(deg[s]); colF[s*64+pos] = d.
__global__ __launch_bounds__(256) void scatter_kernel(const int4* __restrict__ src4,
                                                      const int4* __restrict__ dst4,
                                                      int* __restrict__ deg,
                                                      int* __restrict__ colF) {
    int i = blockIdx.x * 256 + threadIdx.x;
    if (i >= N_EDGES / 4) return;
    int4 s = src4[i];
    int4 d = dst4[i];
    int p0 = atomicAdd(&deg[s.x], 1);
    int p1 = atomicAdd(&deg[s.y], 1);
    int p2 = atomicAdd(&deg[s.z], 1);
    int p3 = atomicAdd(&deg[s.w], 1);
    if (p0 < CAP) colF[(s.x << CAP_BITS) + p0] = d.x;
    if (p1 < CAP) colF[(s.y << CAP_BITS) + p1] = d.y;
    if (p2 < CAP) colF[(s.z << CAP_BITS) + p2] = d.z;
    if (p3 < CAP) colF[(s.w << CAP_BITS) + p3] = d.w;
}

// ---- convert: meta = (deg, dinv); g0 = dinv * x (bf16x2); sentinel row = 0 ----
__global__ __launch_bounds__(256) void convert_kernel(const float4* __restrict__ uw4,
                                                      const float4* __restrict__ iw4,
                                                      const int* __restrict__ deg,
                                                      int2* __restrict__ meta,
                                                      uint2* __restrict__ g0) {
    int i = blockIdx.x * 256 + threadIdx.x;
    const int n = (N_TOTAL + 1) * 16;
    if (i >= n) return;
    int row = i >> 4;
    if (row >= N_TOTAL) { g0[i] = make_uint2(0u, 0u); return; }   // zero dummy row
    int dg = deg[row];
    float di = rsqrtf((float)dg + 1e-8f);
    if ((i & 15) == 0) meta[row] = make_int2(dg, __float_as_int(di));
    float4 x = (row < N_USERS) ? uw4[i] : iw4[i - N_USERS * 16];
    g0[i] = make_uint2(bfpack(di * x.x, di * x.y),
                       bfpack(di * x.z, di * x.w));
}

// ---------------- gather SpMM on pre-scaled g tables (R6 inner loop) -------------
// h_next[row] = dinv[row] * sum_{edges} g_prev[col];  g_next = dinv * h_next.
// Fixed-capacity layout: row's col list at colF[row*64 .. +deg). Each wave handles
// GR=4 rows; lanes 0..3 hold (deg,dinv) meta; row i+1's col window prefetched while
// row i's gathers are in flight. 4 edge streams (16-lane quarters); lane r of
// quarter q covers dims 4r..4r+3 via one dwordx2 load; 16 edges/inner iter.
// Out-of-range shfl slots hold the zero-row sentinel (no bounds logic in the loop).
// MODE 0: out = x + h.  MODE 1: out += h.  MODE 2: out = (out+h)/4, no g_next.
template <int MODE>
__global__ __launch_bounds__(256) void gather_kernel(
        const int2* __restrict__ meta,
        const int* __restrict__ colF,
        const unsigned* __restrict__ gprev,
        unsigned* __restrict__ gnext,
        float4* __restrict__ out4,
        const float4* __restrict__ uw4,
        const float4* __restrict__ iw4) {
    int wid  = blockIdx.x * 4 + (threadIdx.x >> 6);
    int base_row = wid * GR;
    int lane = threadIdx.x & 63;
    int q    = lane >> 4;          // quarter = edge stream
    int r    = lane & 15;          // dims 4r..4r+3
    // lanes 0..GR-1 hold meta (deg, dinv_bits) for rows base_row..+GR-1
    int2 mt = meta[base_row + (lane < GR ? lane : GR - 1)];

    // prefetch row 0's col window
    int d0 = __builtin_amdgcn_readlane(mt.x, 0);
    int myc_cur = (lane < d0) ? colF[(base_row << CAP_BITS) + lane] : SENT;

#pragma unroll
    for (int i = 0; i < GR; ++i) {
        int nd = __builtin_amdgcn_readlane(mt.x, i);
        // prefetch next row's window before draining this row's gathers
        int myc_next = SENT;
        if (i + 1 < GR) {
            int dn = __builtin_amdgcn_readlane(mt.x, i + 1);
            myc_next = (lane < dn) ? colF[((base_row + i + 1) << CAP_BITS) + lane] : SENT;
        }
        f32x2 acc01 = {0.f, 0.f};
        f32x2 acc23 = {0.f, 0.f};
        int n = nd > CAP ? CAP : nd;
        for (int k0 = 0; k0 < n; k0 += 16) {
            int c0 = __shfl(myc_cur, k0 + q);
            int c1 = __shfl(myc_cur, k0 + 4 + q);
            int c2 = __shfl(myc_cur, k0 + 8 + q);
            int c3 = __shfl(myc_cur, k0 + 12 + q);
            uint2 u0 = *(const uint2*)(gprev + ((size_t)(unsigned)c0 << 5) + 2 * r);
            uint2 u1 = *(const uint2*)(gprev + ((size_t)(unsigned)c1 << 5) + 2 * r);
            uint2 u2 = *(const uint2*)(gprev + ((size_t)(unsigned)c2 << 5) + 2 * r);
            uint2 u3 = *(const uint2*)(gprev + ((size_t)(unsigned)c3 << 5) + 2 * r);
            acc01 += bf2(u0.x); acc23 += bf2(u0.y);
            acc01 += bf2(u1.x); acc23 += bf2(u1.y);
            acc01 += bf2(u2.x); acc23 += bf2(u2.y);
            acc01 += bf2(u3.x); acc23 += bf2(u3.y);
        }
        float a0 = acc01.x, a1 = acc01.y, a2 = acc23.x, a3 = acc23.y;
        a0 += __shfl_xor(a0, 16);
        a1 += __shfl_xor(a1, 16);
        a2 += __shfl_xor(a2, 16);
        a3 += __shfl_xor(a3, 16);
        a0 += __shfl_xor(a0, 32);
        a1 += __shfl_xor(a1, 32);
        a2 += __shfl_xor(a2, 32);
        a3 += __shfl_xor(a3, 32);
        float di = __int_as_float(__shfl(mt.y, i));
        if (lane < 16) {
            int row = base_row + i;
            float h0 = di * a0, h1 = di * a1, h2 = di * a2, h3 = di * a3;
            int p = row * 16 + r;
            if (MODE == 0) {
                float4 x = (row < N_USERS) ? uw4[p] : iw4[p - N_USERS * 16];
                ((uint2*)gnext)[p] = make_uint2(bfpack(di * h0, di * h1),
                                                bfpack(di * h2, di * h3));
                out4[p] = make_float4(x.x + h0, x.y + h1, x.z + h2, x.w + h3);
            } else if (MODE == 1) {
                float4 o = out4[p];
                ((uint2*)gnext)[p] = make_uint2(bfpack(di * h0, di * h1),
                                                bfpack(di * h2, di * h3));
                out4[p] = make_float4(o.x + h0, o.y + h1, o.z + h2, o.w + h3);
            } else {
                float4 o = out4[p];
                out4[p] = make_float4((o.x + h0) * 0.25f, (o.y + h1) * 0.25f,
                                      (o.z + h2) * 0.25f, (o.w + h3) * 0.25f);
            }
        }
        myc_cur = myc_next;
    }
    // maintain the zero row of the table the NEXT kernel gathers from
    if (MODE != 2) {
        if (blockIdx.x == 0 && threadIdx.x < 32)
            gnext[(size_t)N_TOTAL * 32 + threadIdx.x] = 0u;
    }
}

extern "C" void kernel_launch(void* const* d_in, const int* in_sizes, int n_in,
                              void* d_out, int out_size, void* d_ws, size_t ws_size,
                              hipStream_t stream) {
    const float* user_w = (const float*)d_in[0];
    const float* item_w = (const float*)d_in[1];
    const int*   src    = (const int*)d_in[2];
    const int*   dst    = (const int*)d_in[3];
    float* out = (float*)d_out;
    (void)in_sizes; (void)n_in; (void)out_size; (void)ws_size;

    char* ws = (char*)d_ws;
    size_t off = 0;
    auto alloc = [&](size_t bytes) {
        char* p = ws + off;
        off = (off + bytes + 255) & ~(size_t)255;
        return p;
    };
    int*      deg  = (int*)     alloc((size_t)N_TOTAL * 4);               // 1.2 MB
    int2*     meta = (int2*)    alloc((size_t)N_TOTAL * 8);               // 2.4 MB
    int*      colF = (int*)     alloc((size_t)N_TOTAL * CAP * 4);         // 76.8 MB
    unsigned* g0   = (unsigned*)alloc((size_t)(N_TOTAL + 1) * 32 * 4);    // 38.4 MB
    unsigned* g_a  = (unsigned*)alloc((size_t)(N_TOTAL + 1) * 32 * 4);    // 38.4 MB

    const float4* uw4 = (const float4*)user_w;
    const float4* iw4 = (const float4*)item_w;
    float4* out4 = (float4*)out;

    const int gatherGrid = N_TOTAL / (4 * GR);   // 18750

    // degree count + fixed-capacity scatter (no partition, no scan)
    hipMemsetAsync(deg, 0, (size_t)N_TOTAL * 4, stream);
    scatter_kernel<<<(N_EDGES / 4 + 255) / 256, 256, 0, stream>>>(
        (const int4*)src, (const int4*)dst, deg, colF);
    // meta (deg, dinv) + g0 = dinv * x (bf16) + sentinel zero row
    convert_kernel<<<((N_TOTAL + 1) * 16 + 255) / 256, 256, 0, stream>>>(
        uw4, iw4, deg, meta, (uint2*)g0);

    // 3 propagation layers; g tables ping-pong (g0 -> g_a -> g0 -> read)
    gather_kernel<0><<<gatherGrid, 256, 0, stream>>>(meta, colF, g0,  g_a,    out4, uw4, iw4);
    gather_kernel<1><<<gatherGrid, 256, 0, stream>>>(meta, colF, g_a, g0,     out4, uw4, iw4);
    gather_kernel<2><<<gatherGrid, 256, 0, stream>>>(meta, colF, g0,  nullptr, out4, uw4, iw4);
}

// Round 11
// 524.160 us; speedup vs baseline: 1.5418x; 1.5418x over previous
//
#include <hip/hip_runtime.h>

#define N_USERS  200000
#define N_ITEMS  100000
#define N_TOTAL  300000
#define EMB_DIM  64
#define N_EDGES  4000000
#define N_LAYERS 3

// radix partition: 256-row buckets, 4096-edge chunks, fixed-capacity regions
#define B2_BITS 8
#define B2_ROWS (1 << B2_BITS)                                     // 256
#define NB2 ((N_TOTAL + B2_ROWS - 1) >> B2_BITS)                   // 1172
#define CHUNK_E 4096
#define NBLK ((N_EDGES + CHUNK_E - 1) / CHUNK_E)                   // 977
#define BCAP_BITS 12
#define BCAP (1 << BCAP_BITS)                                      // 4096/bucket (+11.7 sigma)

// gcur padding: one counter per 64-B cache line
#define GPAD 16

// edge packing: (local_row[8b] << 19) | dst[19b];  N_TOTAL < 2^19
#define DST_BITS 19
#define DST_MASK ((1 << DST_BITS) - 1)

// gather: rows per wave
#define GR 4

typedef float f32x2 __attribute__((ext_vector_type(2)));

// ---- bf16 helpers ----
__device__ __forceinline__ unsigned bfpack(float a, float b) {
    unsigned ua = __float_as_uint(a); ua = (ua + 0x7fffu + ((ua >> 16) & 1u)) >> 16;
    unsigned ub = __float_as_uint(b); ub = (ub + 0x7fffu + ((ub >> 16) & 1u)) >> 16;
    return ua | (ub << 16);
}
__device__ __forceinline__ float bflo(unsigned u) { return __uint_as_float(u << 16); }
__device__ __forceinline__ float bfhi(unsigned u) { return __uint_as_float(u & 0xffff0000u); }
__device__ __forceinline__ f32x2 bf2(unsigned u) {
    f32x2 t; t.x = bflo(u); t.y = bfhi(u); return t;
}

// ---- fused partition: count (LDS) -> reserve (global atomic) -> scatter ----
__global__ __launch_bounds__(512) void part1_kernel(const int* __restrict__ src,
                                                    const int* __restrict__ dst,
                                                    int* __restrict__ gcur,
                                                    int* __restrict__ edgebuf) {
    __shared__ int lcnt[NB2];
    __shared__ int lcur[NB2];
    __shared__ int ssrc[CHUNK_E];
    int blk = blockIdx.x, t = threadIdx.x;
    for (int i = t; i < NB2; i += 512) lcnt[i] = 0;
    __syncthreads();
    int base = blk * CHUNK_E;
    int end = base + CHUNK_E; if (end > N_EDGES) end = N_EDGES;
    for (int e = base + 4 * t; e < end; e += 4 * 512) {
        int4 s4 = *(const int4*)(src + e);
        *(int4*)(ssrc + (e - base)) = s4;
        atomicAdd(&lcnt[s4.x >> B2_BITS], 1);
        atomicAdd(&lcnt[s4.y >> B2_BITS], 1);
        atomicAdd(&lcnt[s4.z >> B2_BITS], 1);
        atomicAdd(&lcnt[s4.w >> B2_BITS], 1);
    }
    __syncthreads();
    for (int i = t; i < NB2; i += 512) {
        int c = lcnt[i];
        int b0 = c ? atomicAdd(&gcur[i * GPAD], c) : 0;
        lcur[i] = (i << BCAP_BITS) + b0;             // absolute write cursor
    }
    __syncthreads();
    for (int e = base + 4 * t; e < end; e += 4 * 512) {
        int4 d4 = *(const int4*)(dst + e);
        int j = e - base;
        int s0 = ssrc[j], s1 = ssrc[j + 1], s2 = ssrc[j + 2], s3 = ssrc[j + 3];
        int p0 = atomicAdd(&lcur[s0 >> B2_BITS], 1);
        edgebuf[p0] = ((s0 & (B2_ROWS - 1)) << DST_BITS) | d4.x;
        int p1 = atomicAdd(&lcur[s1 >> B2_BITS], 1);
        edgebuf[p1] = ((s1 & (B2_ROWS - 1)) << DST_BITS) | d4.y;
        int p2 = atomicAdd(&lcur[s2 >> B2_BITS], 1);
        edgebuf[p2] = ((s2 & (B2_ROWS - 1)) << DST_BITS) | d4.z;
        int p3 = atomicAdd(&lcur[s3 >> B2_BITS], 1);
        edgebuf[p3] = ((s3 & (B2_ROWS - 1)) << DST_BITS) | d4.w;
    }
}

// ---- scan over 1172 bucket totals -> CSR bucket bases; zero sentinel row ----
__global__ void scanT_kernel(const int* __restrict__ gcur, int* __restrict__ bbase,
                             unsigned* __restrict__ g0) {
    __shared__ int lds[512];
    int t = threadIdx.x;
    int base = 4 * t;
    int v[4];
#pragma unroll
    for (int k = 0; k < 4; ++k)
        v[k] = (base + k < NB2) ? gcur[(base + k) * GPAD] : 0;
    int s = v[0] + v[1] + v[2] + v[3];
    lds[t] = s;
    __syncthreads();
    for (int o = 1; o < 512; o <<= 1) {
        int x = (t >= o) ? lds[t - o] : 0;
        __syncthreads();
        lds[t] += x;
        __syncthreads();
    }
    int run = lds[t] - s;       // exclusive
#pragma unroll
    for (int k = 0; k < 4; ++k) {
        if (base + k < NB2) bbase[base + k] = run;
        run += v[k];
    }
    if (t == 511) bbase[NB2] = lds[511];
    if (t < 32) g0[(size_t)N_TOTAL * 32 + t] = 0u;   // zero dummy row
}

// ---- fused fine pass: per-bucket hist+scan -> offs/dinv, scatter col, write g0 ----
__global__ __launch_bounds__(512) void part2_kernel(const int* __restrict__ gcur,
                                                    const int* __restrict__ bbase,
                                                    const int* __restrict__ edgebuf,
                                                    int* __restrict__ col,
                                                    int* __restrict__ offs,
                                                    float* __restrict__ dinv,
                                                    const float4* __restrict__ uw4,
                                                    const float4* __restrict__ iw4,
                                                    uint2* __restrict__ g0) {
    __shared__ int lhist[B2_ROWS];    // counts, then running write cursors
    __shared__ int lsums[B2_ROWS];    // scan workspace, then dinv stash
    __shared__ int lbuf[BCAP];        // staged bucket edges (single global read)
    int b = blockIdx.x;
    int base = b << B2_BITS;
    int nrows = N_TOTAL - base; if (nrows > B2_ROWS) nrows = B2_ROWS;
    int t = threadIdx.x;
    int cnt    = gcur[b * GPAD];
    int bstart = bbase[b];
    int ebase  = b << BCAP_BITS;

    if (t < B2_ROWS) lhist[t] = 0;
    __syncthreads();
    // pass 1: stage + per-row counts
    for (int j = t; j < cnt; j += 512) {
        int e = edgebuf[ebase + j];
        lbuf[j] = e;
        atomicAdd(&lhist[e >> DST_BITS], 1);
    }
    __syncthreads();
    // exclusive scan of 256 counts (first 256 threads)
    int v = (t < B2_ROWS) ? lhist[t] : 0;
    if (t < B2_ROWS) lsums[t] = v;
    __syncthreads();
    for (int o = 1; o < B2_ROWS; o <<= 1) {
        int x = (t >= o && t < B2_ROWS) ? lsums[t - o] : 0;
        __syncthreads();
        if (t < B2_ROWS) lsums[t] += x;
        __syncthreads();
    }
    int o0 = 0;
    float dv = 0.f;
    if (t < B2_ROWS) {
        o0 = bstart + lsums[t] - v;         // exclusive row offset
        dv = rsqrtf((float)v + 1e-8f);
    }
    if (t < nrows) {
        offs[base + t] = o0;
        dinv[base + t] = dv;
    }
    if (b == NB2 - 1 && t == 0) offs[N_TOTAL] = N_EDGES;
    __syncthreads();
    if (t < B2_ROWS) {
        lhist[t] = o0;                       // reuse as write cursors
        lsums[t] = __float_as_int(dv);       // stash dinv for g0 writer
    }
    __syncthreads();
    // pass 2: scatter dst into row-sorted col (from LDS)
    for (int j = t; j < cnt; j += 512) {
        int e = lbuf[j];
        int pos = atomicAdd(&lhist[e >> DST_BITS], 1);
        col[pos] = e & DST_MASK;
    }
    // fused convert: g0[row] = dinv[row] * x[row] (bf16x2 packed)
    int np = nrows << 4;
    for (int p = t; p < np; p += 512) {
        int rl = p >> 4, rr = p & 15;
        int row = base + rl;
        float di = __int_as_float(lsums[rl]);
        float4 x = (row < N_USERS) ? uw4[row * 16 + rr]
                                   : iw4[(row - N_USERS) * 16 + rr];
        g0[row * 16 + rr] = make_uint2(bfpack(di * x.x, di * x.y),
                                       bfpack(di * x.z, di * x.w));
    }
}

// ---------------- gather SpMM on pre-scaled g tables ----------------
// h_k = di * sum(g_{k-1});  g_k = di * h_k (bf16, persisted).
// Key algebra: out = x + (g_a + g_b)/di + h3 — so layers 1-2 write ONLY their
// g table (no out traffic); the final layer reconstructs h1+h2 from g_a,g_b.
// Wave structure (R6-proven): GR=4 rows/wave, cross-row col-window prefetch,
// 4 edge streams (16-lane quarters), lane r covers dims 4r..4r+3 (dwordx2),
// 16 edges in flight; sentinel zero row for tails.
// MODE 0/1: gnext = di*h (bf16) only.
// MODE 2:   out = x + (gA + gprev_row)/di + h3  (gA = g_a; gprev = g_b).
template <int MODE>
__global__ __launch_bounds__(256) void gather_kernel(
        const int* __restrict__ offs,
        const int* __restrict__ col,
        const float* __restrict__ dinv,
        const unsigned* __restrict__ gprev,
        unsigned* __restrict__ gnext,
        const unsigned* __restrict__ gA,
        float4* __restrict__ out4,
        const float4* __restrict__ uw4,
        const float4* __restrict__ iw4) {
    int wid  = blockIdx.x * 4 + (threadIdx.x >> 6);
    int base_row = wid * GR;
    int lane = threadIdx.x & 63;
    int q    = lane >> 4;          // quarter = edge stream
    int r    = lane & 15;          // dims 4r..4r+3
    int li = lane < GR ? lane : GR;
    int off_l = offs[base_row + li];
    float dv  = dinv[base_row + (lane < GR ? lane : GR - 1)];

    // prefetch row 0's first col window
    int s0 = __builtin_amdgcn_readlane(off_l, 0);
    int e0 = __builtin_amdgcn_readlane(off_l, 1);
    int myc_cur = (lane < e0 - s0) ? col[s0 + lane] : N_TOTAL;

#pragma unroll
    for (int i = 0; i < GR; ++i) {
        int start = __builtin_amdgcn_readlane(off_l, i);
        int end   = __builtin_amdgcn_readlane(off_l, i + 1);
        // prefetch next row's first window
        int myc_next = N_TOTAL;
        if (i + 1 < GR) {
            int sn = __builtin_amdgcn_readlane(off_l, i + 1);
            int en = __builtin_amdgcn_readlane(off_l, i + 2);
            myc_next = (lane < en - sn) ? col[sn + lane] : N_TOTAL;
        }
        f32x2 acc01 = {0.f, 0.f};
        f32x2 acc23 = {0.f, 0.f};
        int n = end - start; if (n > 64) n = 64;
        for (int k0 = 0; k0 < n; k0 += 16) {
            int c0 = __shfl(myc_cur, k0 + q);
            int c1 = __shfl(myc_cur, k0 + 4 + q);
            int c2 = __shfl(myc_cur, k0 + 8 + q);
            int c3 = __shfl(myc_cur, k0 + 12 + q);
            uint2 u0 = *(const uint2*)(gprev + ((size_t)(unsigned)c0 << 5) + 2 * r);
            uint2 u1 = *(const uint2*)(gprev + ((size_t)(unsigned)c1 << 5) + 2 * r);
            uint2 u2 = *(const uint2*)(gprev + ((size_t)(unsigned)c2 << 5) + 2 * r);
            uint2 u3 = *(const uint2*)(gprev + ((size_t)(unsigned)c3 << 5) + 2 * r);
            acc01 += bf2(u0.x); acc23 += bf2(u0.y);
            acc01 += bf2(u1.x); acc23 += bf2(u1.y);
            acc01 += bf2(u2.x); acc23 += bf2(u2.y);
            acc01 += bf2(u3.x); acc23 += bf2(u3.y);
        }
        // rare: rows with degree > 64
        for (int cb = start + 64; cb < end; cb += 64) {
            int rem = end - cb;
            int nn = rem > 64 ? 64 : rem;
            int myc = (lane < rem) ? col[cb + lane] : N_TOTAL;
            for (int k0 = 0; k0 < nn; k0 += 16) {
                int c0 = __shfl(myc, k0 + q);
                int c1 = __shfl(myc, k0 + 4 + q);
                int c2 = __shfl(myc, k0 + 8 + q);
                int c3 = __shfl(myc, k0 + 12 + q);
                uint2 u0 = *(const uint2*)(gprev + ((size_t)(unsigned)c0 << 5) + 2 * r);
                uint2 u1 = *(const uint2*)(gprev + ((size_t)(unsigned)c1 << 5) + 2 * r);
                uint2 u2 = *(const uint2*)(gprev + ((size_t)(unsigned)c2 << 5) + 2 * r);
                uint2 u3 = *(const uint2*)(gprev + ((size_t)(unsigned)c3 << 5) + 2 * r);
                acc01 += bf2(u0.x); acc23 += bf2(u0.y);
                acc01 += bf2(u1.x); acc23 += bf2(u1.y);
                acc01 += bf2(u2.x); acc23 += bf2(u2.y);
                acc01 += bf2(u3.x); acc23 += bf2(u3.y);
            }
        }
        float a0 = acc01.x, a1 = acc01.y, a2 = acc23.x, a3 = acc23.y;
        a0 += __shfl_xor(a0, 16);
        a1 += __shfl_xor(a1, 16);
        a2 += __shfl_xor(a2, 16);
        a3 += __shfl_xor(a3, 16);
        a0 += __shfl_xor(a0, 32);
        a1 += __shfl_xor(a1, 32);
        a2 += __shfl_xor(a2, 32);
        a3 += __shfl_xor(a3, 32);
        float di = __shfl(dv, i);
        if (lane < 16) {
            int row = base_row + i;
            float h0 = di * a0, h1 = di * a1, h2 = di * a2, h3 = di * a3;
            int p = row * 16 + r;
            if (MODE == 0 || MODE == 1) {
                // layers 1-2: persist g only; out untouched (reconstructed later)
                ((uint2*)gnext)[p] = make_uint2(bfpack(di * h0, di * h1),
                                                bfpack(di * h2, di * h3));
            } else {
                // final: out = x + (g_a + g_b)/di + h3
                float rdi = 1.0f / di;
                uint2 a2v = ((const uint2*)gA)[p];        // g_a row (bf16)
                uint2 b2v = ((const uint2*)gprev)[p];     // g_b row (bf16)
                float4 x = (row < N_USERS) ? uw4[p] : iw4[p - N_USERS * 16];
                float s0f = (bflo(a2v.x) + bflo(b2v.x)) * rdi;
                float s1f = (bfhi(a2v.x) + bfhi(b2v.x)) * rdi;
                float s2f = (bflo(a2v.y) + bflo(b2v.y)) * rdi;
                float s3f = (bfhi(a2v.y) + bfhi(b2v.y)) * rdi;
                out4[p] = make_float4((x.x + s0f + h0) * 0.25f,
                                      (x.y + s1f + h1) * 0.25f,
                                      (x.z + s2f + h2) * 0.25f,
                                      (x.w + s3f + h3) * 0.25f);
            }
        }
        myc_cur = myc_next;
    }
    // maintain the zero row of the table the NEXT kernel gathers from
    if (MODE != 2) {
        if (blockIdx.x == 0 && threadIdx.x < 32)
            gnext[(size_t)N_TOTAL * 32 + threadIdx.x] = 0u;
    }
}

extern "C" void kernel_launch(void* const* d_in, const int* in_sizes, int n_in,
                              void* d_out, int out_size, void* d_ws, size_t ws_size,
                              hipStream_t stream) {
    const float* user_w = (const float*)d_in[0];
    const float* item_w = (const float*)d_in[1];
    const int*   src    = (const int*)d_in[2];
    const int*   dst    = (const int*)d_in[3];
    float* out = (float*)d_out;
    (void)in_sizes; (void)n_in; (void)out_size; (void)ws_size;

    char* ws = (char*)d_ws;
    size_t off = 0;
    auto alloc = [&](size_t bytes) {
        char* p = ws + off;
        off = (off + bytes + 255) & ~(size_t)255;
        return p;
    };
    int*      gcur   = (int*)     alloc((size_t)NB2 * GPAD * 4);         // 75 KB (padded)
    int*      bbase  = (int*)     alloc((size_t)(NB2 + 1) * 4);
    int*      offs   = (int*)     alloc((size_t)(N_TOTAL + 1) * 4);
    float*    dinv   = (float*)   alloc((size_t)N_TOTAL * 4);
    int*      col    = (int*)     alloc((size_t)N_EDGES * 4);            // 16 MB
    int*      edgebuf= (int*)     alloc((size_t)NB2 * BCAP * 4);         // 19.2 MB
    unsigned* g0     = (unsigned*)alloc((size_t)(N_TOTAL + 1) * 32 * 4); // 38.4 MB
    unsigned* g_a    = (unsigned*)alloc((size_t)(N_TOTAL + 1) * 32 * 4); // 38.4 MB
    unsigned* g_b    = (unsigned*)alloc((size_t)(N_TOTAL + 1) * 32 * 4); // 38.4 MB

    const int B = 256;
    const int gatherGrid = N_TOTAL / (4 * GR);   // 18750

    const float4* uw4 = (const float4*)user_w;
    const float4* iw4 = (const float4*)item_w;
    float4* out4 = (float4*)out;

    // fused partition into fixed-capacity bucket regions
    hipMemsetAsync(gcur, 0, (size_t)NB2 * GPAD * 4, stream);
    part1_kernel<<<NBLK, 512, 0, stream>>>(src, dst, gcur, edgebuf);
    // bucket bases (1172-entry scan) + g0 sentinel row
    scanT_kernel<<<1, 512, 0, stream>>>(gcur, bbase, g0);
    // per-bucket hist+scan -> offs/dinv, scatter col, fused g0 convert
    part2_kernel<<<NB2, 512, 0, stream>>>(gcur, bbase, edgebuf, col, offs, dinv,
                                          uw4, iw4, (uint2*)g0);

    // layers: D1,D2 write only their g tables; D3 reconstructs out
    gather_kernel<0><<<gatherGrid, B, 0, stream>>>(offs, col, dinv, g0,  g_a, nullptr, out4, uw4, iw4);
    gather_kernel<1><<<gatherGrid, B, 0, stream>>>(offs, col, dinv, g_a, g_b, nullptr, out4, uw4, iw4);
    gather_kernel<2><<<gatherGrid, B, 0, stream>>>(offs, col, dinv, g_b, nullptr, g_a, out4, uw4, iw4);
}